// Round 6
// baseline (337.726 us; speedup 1.0000x reference)
//
#include <hip/hip_runtime.h>
#include <math.h>
#include <type_traits>

typedef float f2 __attribute__((ext_vector_type(2)));
typedef float f4 __attribute__((ext_vector_type(4)));

#define DD 160
#define HH 160
#define WW 160
#define BB 4
#define KK 11
#define RAD 5
#define TH 16                     // H rows per tile
#define TW 32                     // W cols per tile
#define DCH 32
#define NPLANES (DCH + 2 * RAD)   // 42 (loop padded to 44 = 4*11)
#define NDCH (DD / DCH)           // 5
#define HALO_H (TH + 2 * RAD)     // 26
#define TS 32                     // tmp row stride: 4 words/bank = b64 floor, conflict-free
#define STAT (HALO_H * TS)        // 832 floats per stat plane

struct GaussW { float g[KK]; };

__global__ __launch_bounds__(256, 2)
void ssim3d_kernel(const float* __restrict__ img1,
                   const float* __restrict__ img2,
                   float* __restrict__ out, GaussW gw)
{
    __shared__ float tmpA[5 * STAT];   // 16.6 KB, double buffer via pointer swap
    __shared__ float tmpB[5 * STAT];
    __shared__ float wsum[4];

    const int tid = threadIdx.x;        // 256 threads = 4 waves
    // phase-2 mapping: 16 rows x 16 col-pairs
    const int xc = tid & 15;            // cols 2xc, 2xc+1
    const int ty = tid >> 4;            // 0..15
    // phase-1 mapping: 26 rows x 8 quads (208 active)
    const int p1r = tid >> 3;           // 0..31 (<26 active)
    const int p1q = tid & 7;            // quad -> tmp cols 4q..4q+3

    const int blk = blockIdx.x;
    const int bw = blk % 5;                   // 5 W tiles of 32
    const int bh = (blk / 5) % 10;            // 10 H tiles of 16
    const int bd = (blk / 50) % NDCH;
    const int bb = blk / (50 * NDCH);

    const int oh0 = bh * TH, ow0 = bw * TW, od0 = bd * DCH;
    const float* base1 = img1 + (size_t)bb * DD * HH * WW;
    const float* base2 = img2 + (size_t)bb * DD * HH * WW;

    float g[KK];
#pragma unroll
    for (int i = 0; i < KK; ++i) g[i] = gw.g[i];

    // static D-ring: slot s holds output q with q % 11 == s (f2 = 2 W-cols)
    f2 a1[KK], a2[KK], a11[KK], a22[KK], a12[KK];
#pragma unroll
    for (int i = 0; i < KK; ++i) { a1[i]=0.f; a2[i]=0.f; a11[i]=0.f; a22[i]=0.f; a12[i]=0.f; }

    f2 lsum = 0.f;

    // phase-1 per-thread constants
    const int gh = oh0 - RAD + p1r;
    const bool p1act = (p1r < HALO_H);
    const bool rowok = p1act && ((unsigned)gh < (unsigned)HH);
    const int gc0 = ow0 + 4 * p1q - 8;                    // first loaded col (16B aligned)
    const size_t rowoff = (size_t)((unsigned)gh < (unsigned)HH ? gh : 0) * WW;

    // prefetch registers: next plane's 20 cols per thread
    f4 pa[5], pb[5];
#pragma unroll
    for (int j = 0; j < 5; ++j) { pa[j] = (f4)0.f; pb[j] = (f4)0.f; }

    float* twr = tmpA;
    float* trd = tmpB;

    // preamble: prefetch plane p=0 if valid
    {
        const int dn = od0 - RAD;
        if (p1act && (unsigned)dn < (unsigned)DD) {
            const size_t pbv = (size_t)dn * (HH * WW) + rowoff;
#pragma unroll
            for (int j = 0; j < 5; ++j) {
                const int gc = gc0 + 4 * j;
                f4 za = (f4)0.f, zb = (f4)0.f;
                if (rowok && gc >= 0 && gc <= WW - 4) {
                    za = *(const f4*)(base1 + pbv + gc);
                    zb = *(const f4*)(base2 + pbv + gc);
                }
                pa[j] = za; pb[j] = zb;
            }
        }
    }

    int pcbase = 0;
    auto body = [&](auto uc) {
        constexpr int U = decltype(uc)::value;
        const int p = pcbase + U;
        const int d = od0 - RAD + p;
        const bool dval = (p < NPLANES) && ((unsigned)d < (unsigned)DD);  // block-uniform

        // ---- phase 1: W-conv of 5 stats from prefetched regs ----
        if (dval && p1act) {
            float t1[4]  = {0.f,0.f,0.f,0.f};
            float t2[4]  = {0.f,0.f,0.f,0.f};
            float t11[4] = {0.f,0.f,0.f,0.f};
            float t22[4] = {0.f,0.f,0.f,0.f};
            float t12[4] = {0.f,0.f,0.f,0.f};
#pragma unroll
            for (int j = 0; j < 5; ++j) {
#pragma unroll
                for (int ii = 0; ii < 4; ++ii) {
                    const int i = 4 * j + ii;          // local col 0..19; need 3..16
                    if (i < 3 || i > 16) continue;
                    const float av = pa[j][ii], bv = pb[j][ii];
                    const float aa = av * av, bb2 = bv * bv, ab = av * bv;
#pragma unroll
                    for (int m = 0; m < 4; ++m) {
                        const int k = i - m - 3;       // tap index
                        if (k >= 0 && k < KK) {
                            const float w = g[k];
                            t1[m]  += w * av;
                            t2[m]  += w * bv;
                            t11[m] += w * aa;
                            t22[m] += w * bb2;
                            t12[m] += w * ab;
                        }
                    }
                }
            }
            float* tw = twr + p1r * TS + 4 * p1q;      // 16B-aligned, 8 words/bank floor
            f4 v;
            v[0]=t1[0];  v[1]=t1[1];  v[2]=t1[2];  v[3]=t1[3];  *(f4*)(tw + 0*STAT) = v;
            v[0]=t2[0];  v[1]=t2[1];  v[2]=t2[2];  v[3]=t2[3];  *(f4*)(tw + 1*STAT) = v;
            v[0]=t11[0]; v[1]=t11[1]; v[2]=t11[2]; v[3]=t11[3]; *(f4*)(tw + 2*STAT) = v;
            v[0]=t22[0]; v[1]=t22[1]; v[2]=t22[2]; v[3]=t22[3]; *(f4*)(tw + 3*STAT) = v;
            v[0]=t12[0]; v[1]=t12[1]; v[2]=t12[2]; v[3]=t12[3]; *(f4*)(tw + 4*STAT) = v;
        }

        if (dval) __syncthreads();   // drains only LDS writes; prefetch not yet issued

        // ---- prefetch plane p+1 AFTER the barrier: stays in flight through
        //      phase 2 + next phase 1 address calc, waited only at first use ----
        {
            const int pn = p + 1;
            const int dn = od0 - RAD + pn;
            if (p1act && (pn < NPLANES) && ((unsigned)dn < (unsigned)DD)) {
                const size_t pbv = (size_t)dn * (HH * WW) + rowoff;
#pragma unroll
                for (int j = 0; j < 5; ++j) {
                    const int gc = gc0 + 4 * j;
                    f4 za = (f4)0.f, zb = (f4)0.f;
                    if (rowok && gc >= 0 && gc <= WW - 4) {
                        za = *(const f4*)(base1 + pbv + gc);
                        zb = *(const f4*)(base2 + pbv + gc);
                    }
                    pa[j] = za; pb[j] = zb;
                }
            }
        }

        // ---- phase 2: H-conv (f2 b64, conflict-free) + static-slot D scatter ----
        if (dval) {
            f2 P1 = 0.f, P2 = 0.f, P11 = 0.f, P22 = 0.f, P12 = 0.f;
            const float* tb = twr + (ty * TS + 2 * xc);
#pragma unroll
            for (int k = 0; k < KK; ++k) {
                const float w = g[k];
                const int o = k * TS;
                P1  += w * *(const f2*)(tb + 0*STAT + o);
                P2  += w * *(const f2*)(tb + 1*STAT + o);
                P11 += w * *(const f2*)(tb + 2*STAT + o);
                P22 += w * *(const f2*)(tb + 3*STAT + o);
                P12 += w * *(const f2*)(tb + 4*STAT + o);
            }
#pragma unroll
            for (int t = 0; t < KK; ++t) {
                constexpr int base = U + 22;
                const int s = (base - t) % 11;         // compile-time folds
                const float w = g[t];
                a1[s]  += w * P1;
                a2[s]  += w * P2;
                a11[s] += w * P11;
                a22[s] += w * P22;
                a12[s] += w * P12;
            }
        }

        // ---- emit output q = p-10 from fixed slot (U+1)%11, then zero it ----
        constexpr int e = (U + 1) % 11;
        if (p >= 2 * RAD && p < NPLANES) {
            f2 mu1 = a1[e], mu2 = a2[e];
            f2 m11 = mu1 * mu1, m22 = mu2 * mu2, m12 = mu1 * mu2;
            f2 sg1 = a11[e] - m11, sg2 = a22[e] - m22, sg12 = a12[e] - m12;
            const float C1c = 0.0001f, C2c = 0.0009f;
            f2 num = (2.f * m12 + C1c) * (2.f * sg12 + C2c);
            f2 den = (m11 + m22 + C1c) * (sg1 + sg2 + C2c);
            lsum += num / den;
        }
        a1[e] = 0.f; a2[e] = 0.f; a11[e] = 0.f; a22[e] = 0.f; a12[e] = 0.f;

        // swap double buffers
        float* t = twr; twr = trd; trd = t;
    };

    for (pcbase = 0; pcbase < 44; pcbase += 11) {
        body(std::integral_constant<int, 0>{});
        body(std::integral_constant<int, 1>{});
        body(std::integral_constant<int, 2>{});
        body(std::integral_constant<int, 3>{});
        body(std::integral_constant<int, 4>{});
        body(std::integral_constant<int, 5>{});
        body(std::integral_constant<int, 6>{});
        body(std::integral_constant<int, 7>{});
        body(std::integral_constant<int, 8>{});
        body(std::integral_constant<int, 9>{});
        body(std::integral_constant<int, 10>{});
    }

    // ---- reduction: wave shuffle -> LDS -> one atomic per block ----
    float v = lsum.x + lsum.y;
#pragma unroll
    for (int off = 32; off > 0; off >>= 1)
        v += __shfl_down(v, off, 64);
    if ((tid & 63) == 0) wsum[tid >> 6] = v;
    __syncthreads();
    if (tid == 0) {
        const float inv_n = 1.0f / ((float)BB * DD * HH * WW);
        atomicAdd(out, (wsum[0] + wsum[1] + wsum[2] + wsum[3]) * inv_n);
    }
}

extern "C" void kernel_launch(void* const* d_in, const int* in_sizes, int n_in,
                              void* d_out, int out_size, void* d_ws, size_t ws_size,
                              hipStream_t stream) {
    const float* img1 = (const float*)d_in[0];
    const float* img2 = (const float*)d_in[1];
    float* out = (float*)d_out;

    GaussW gw;
    double gd[KK], sum = 0.0;
    for (int i = 0; i < KK; ++i) {
        double x = (double)(i - KK / 2);
        gd[i] = exp(-(x * x) / (2.0 * 1.5 * 1.5));
        sum += gd[i];
    }
    for (int i = 0; i < KK; ++i) gw.g[i] = (float)(gd[i] / sum);

    hipMemsetAsync(d_out, 0, sizeof(float), stream);

    dim3 grid(5 * 10 * NDCH * BB);   // 1000 blocks — whole grid co-resident
    dim3 block(256);
    hipLaunchKernelGGL(ssim3d_kernel, grid, block, 0, stream,
                       img1, img2, out, gw);
}